// Round 22
// baseline (187.344 us; speedup 1.0000x reference)
//
#include <hip/hip_runtime.h>
#include <cfloat>
#include <cmath>

#define M     16384
#define K     4096
#define E     64
#define TOPK  8
#define GAP_THRESH 1e-4f

#define NCH   (K / 32)          // 128 chunks of k32 (full K per block)
#define RCAP  2048              // max rescued rows
#define FKS   8                 // rescue K-split

typedef __attribute__((ext_vector_type(8))) short bf16x8;
typedef __attribute__((ext_vector_type(4))) float f32x4;

// ws layout: [Whf 512K][Wlf 512K][count 256B][list 64KB][dsum 8MB]

__device__ __forceinline__ short f2bf(float f) {           // RNE fp32->bf16
    unsigned u = __builtin_bit_cast(unsigned, f);
    u += 0x7FFFu + ((u >> 16) & 1u);
    return (short)(u >> 16);
}
__device__ __forceinline__ float bf2f(short h) {           // exact widen
    unsigned u = ((unsigned)(unsigned short)h) << 16;
    return __builtin_bit_cast(float, u);
}

// ---------------------------------------------------------------------------
// prep (r17-r21 byte-identical): Whf/Wlf in MFMA fragment order; zero count.
// ---------------------------------------------------------------------------
__global__ __launch_bounds__(256) void prep_kernel(const float* __restrict__ W,
                                                   short* __restrict__ Whf,
                                                   short* __restrict__ Wlf,
                                                   int* __restrict__ count) {
    int t = blockIdx.x * 256 + threadIdx.x;   // t = e*4096 + k
    float w = W[t];
    short h = f2bf(w);
    short lo = f2bf(w - bf2f(h));
    int e = t >> 12, k = t & 4095;
    int gc = k >> 5, kk = k & 31;
    size_t fidx = (((size_t)gc * 4 + (e >> 4)) * 64 + (kk >> 3) * 16 + (e & 15)) * 8
                  + (kk & 7);
    Whf[fidx] = h;
    Wlf[fidx] = lo;
    if (t == 0) *count = 0;
}

// ---------------------------------------------------------------------------
// MFMA gate, r22: fused SPLIT=1 epilogue (r21-proven) + EXPERT-SPLIT waves.
// r21's regression was 1 wave/SIMD starvation (grid 256).  Now: block =
// 4 waves sharing the SAME 16 x-rows (L1-shared loads), each wave owns 16
// experts (et = wv) -> grid = M/16 = 1024 = 4 blocks/CU = 16 waves/CU with
// NO partials buffer and NO reduce kernel.  Per chunk per wave: 2 x float4
// + 1KB Wh + 1KB Wl (own et) + cvt + 3 MFMA, in the r12-proven 2-deep named
// pipeline.  One barrier before the fused epilogue (llog is cross-wave);
// each wave epilogues 4 rows with the proven ballot top-9 + flag.
// ---------------------------------------------------------------------------
struct XW {
    float4 xa, xb;
    bf16x8 h, lo;
};

__device__ __forceinline__ void load_set(XW& s, const float* gx,
                                         const short* ph, const short* pl, int cc) {
    const int ko = cc * 32;
    s.xa = *reinterpret_cast<const float4*>(gx + ko);
    s.xb = *reinterpret_cast<const float4*>(gx + ko + 4);
    s.h  = *reinterpret_cast<const bf16x8*>(ph + (size_t)cc * 2048);
    s.lo = *reinterpret_cast<const bf16x8*>(pl + (size_t)cc * 2048);
}

__device__ __forceinline__ void compute_set(const XW& s, f32x4& acc) {
    float vv[8] = {s.xa.x, s.xa.y, s.xa.z, s.xa.w, s.xb.x, s.xb.y, s.xb.z, s.xb.w};
    bf16x8 ah, al;
#pragma unroll
    for (int j = 0; j < 8; ++j) {
        short hh = f2bf(vv[j]);
        ah[j] = hh;
        al[j] = f2bf(vv[j] - bf2f(hh));
    }
    acc = __builtin_amdgcn_mfma_f32_16x16x32_bf16(ah, s.h,  acc, 0, 0, 0);
    acc = __builtin_amdgcn_mfma_f32_16x16x32_bf16(ah, s.lo, acc, 0, 0, 0);
    acc = __builtin_amdgcn_mfma_f32_16x16x32_bf16(al, s.h,  acc, 0, 0, 0);
}

__global__ __launch_bounds__(256) void gate_kernel(
    const float* __restrict__ x,
    const short* __restrict__ Whf,
    const short* __restrict__ Wlf,
    const float* __restrict__ b,
    float* __restrict__ outp,
    float* __restrict__ outi,
    int*   __restrict__ count,
    int*   __restrict__ list)
{
    __shared__ float llog[16 * E];       // 4 KB logit tile (16 rows x 64 e)

    const int t  = threadIdx.x;
    const int l  = t & 63;
    const int wv = t >> 6;               // 0..3 = expert group (et)
    const int row0 = blockIdx.x * 16;

    const int kg   = l >> 4;             // 0..3 k-granule
    const int xrow = row0 + (l & 15);

    const float* gx = x + (size_t)xrow * K + kg * 8;
    // fragment-ordered W: (gc*4 + et) blocks of 512 shorts; et = wv
    const short* ph = Whf + (size_t)wv * 512 + (size_t)l * 8;
    const short* pl = Wlf + (size_t)wv * 512 + (size_t)l * 8;

    f32x4 acc = {0, 0, 0, 0};

    XW A, B;
    load_set(A, gx, ph, pl, 0);
    for (int c = 0; c < NCH; c += 2) {
        load_set(B, gx, ph, pl, c + 1);
        compute_set(A, acc);
        if (c + 2 < NCH) load_set(A, gx, ph, pl, c + 2);
        compute_set(B, acc);
    }

    // D layout (verified r10-r21): row = (l>>4)*4 + r, col = wv*16 + (l&15)
#pragma unroll
    for (int r = 0; r < 4; ++r)
        llog[((l >> 4) * 4 + r) * E + wv * 16 + (l & 15)] = acc[r];
    __syncthreads();

    const float bv = b[l];
#pragma unroll 1
    for (int rr = 0; rr < 4; ++rr) {
        const int rloc = wv * 4 + rr;
        const int row  = row0 + rloc;
        const float orig = llog[rloc * E + l] + bv;

        // proven fp32 top-9 ballot epilogue (r3-r21)
        float cur = orig;
        float vals[9];
        float myidxf = 0.0f;
        bool  sel = false;

#pragma unroll
        for (int i = 0; i < 9; ++i) {
            float m = cur;
#pragma unroll
            for (int off = 32; off > 0; off >>= 1)
                m = fmaxf(m, __shfl_xor(m, off, 64));
            unsigned long long msk = __ballot(cur == m);
            int il = __ffsll((long long)msk) - 1;
            vals[i] = m;
            if (l == il) { cur = -FLT_MAX; if (i < TOPK) sel = true; }
            if (i < TOPK && l == i) myidxf = (float)il;
        }

        float ssum = 0.0f;
#pragma unroll
        for (int i = 0; i < TOPK; ++i) ssum += expf(vals[i] - vals[0]);
        float p = sel ? (expf(orig - vals[0]) / ssum) : 0.0f;

        outp[(size_t)row * E + l] = p;
        if (l < TOPK) outi[(size_t)row * TOPK + l] = myidxf;

        float mingap = FLT_MAX;
#pragma unroll
        for (int i = 0; i < 8; ++i) mingap = fminf(mingap, vals[i] - vals[i + 1]);
        if (l == 0 && mingap < GAP_THRESH) {
            int pos = atomicAdd(count, 1);
            if (pos < M) list[pos] = row;
        }
    }
}

// ---------------------------------------------------------------------------
// fix1 (r20/r21 byte-identical): fp64 partial dots, K-split 8 across blocks.
// ---------------------------------------------------------------------------
__global__ __launch_bounds__(256) void fix1_kernel(
    const float* __restrict__ x,
    const float* __restrict__ W,
    double* __restrict__ dsum,          // [RCAP][FKS][E]
    const int* __restrict__ count,
    const int* __restrict__ list)
{
    __shared__ float xsl[512];
    const int t   = threadIdx.x;
    const int l   = t & 63;
    const int wv  = t >> 6;
    const int tot = min(*count, RCAP) * FKS;

    for (int p = blockIdx.x; p < tot; p += gridDim.x) {
        const int i   = p >> 3;
        const int ks  = p & 7;
        const int row = list[i];
        const int k0  = ks << 9;

        if (t < 128)
            reinterpret_cast<float4*>(xsl)[t] =
                reinterpret_cast<const float4*>(x + (size_t)row * K + k0)[t];
        __syncthreads();

        const float4* xs4 = reinterpret_cast<const float4*>(xsl);

#pragma unroll
        for (int g = 0; g < 2; ++g) {
            const int e0 = wv * 16 + g * 8;
            float4 w0[8], w1[8];
#pragma unroll
            for (int e8 = 0; e8 < 8; ++e8) {
                const float4* wp = reinterpret_cast<const float4*>(
                    W + (size_t)(e0 + e8) * K + k0);
                w0[e8] = wp[l];
                w1[e8] = wp[l + 64];
            }
            float4 xv0 = xs4[l];
            float4 xv1 = xs4[l + 64];

            double s[8];
#pragma unroll
            for (int e8 = 0; e8 < 8; ++e8) {
                double a = 0.0;
                a = fma((double)xv0.x, (double)w0[e8].x, a);
                a = fma((double)xv0.y, (double)w0[e8].y, a);
                a = fma((double)xv0.z, (double)w0[e8].z, a);
                a = fma((double)xv0.w, (double)w0[e8].w, a);
                a = fma((double)xv1.x, (double)w1[e8].x, a);
                a = fma((double)xv1.y, (double)w1[e8].y, a);
                a = fma((double)xv1.z, (double)w1[e8].z, a);
                a = fma((double)xv1.w, (double)w1[e8].w, a);
                s[e8] = a;
            }

#pragma unroll
            for (int e8 = 0; e8 < 8; ++e8) {
                double v = s[e8];
#pragma unroll
                for (int off = 32; off > 0; off >>= 1)
                    v += __shfl_xor(v, off, 64);
                if (l == 0)
                    dsum[((size_t)i * FKS + ks) * E + e0 + e8] = v;
            }
        }
        __syncthreads();
    }
}

// ---------------------------------------------------------------------------
// fix2 (r20/r21 byte-identical): combine partials + proven fp64 epilogue.
// ---------------------------------------------------------------------------
__global__ __launch_bounds__(64) void fix2_kernel(
    const double* __restrict__ dsum,
    const float*  __restrict__ b,
    float* __restrict__ outp,
    float* __restrict__ outi,
    const int* __restrict__ count,
    const int* __restrict__ list)
{
    const int l   = threadIdx.x;
    const int cnt = min(*count, RCAP);

    for (int i = blockIdx.x; i < cnt; i += gridDim.x) {
        const int row = list[i];

        double orig = (double)b[l];
#pragma unroll
        for (int ks = 0; ks < FKS; ++ks)
            orig += dsum[((size_t)i * FKS + ks) * E + l];

        double cur = orig;
        double vals[TOPK];
        float  myidxf = 0.0f;
        bool   sel = false;

#pragma unroll
        for (int tt = 0; tt < TOPK; ++tt) {
            double m = cur;
#pragma unroll
            for (int off = 32; off > 0; off >>= 1) {
                double o = __shfl_xor(m, off, 64);
                m = fmax(m, o);
            }
            unsigned long long msk = __ballot(cur == m);
            int il = __ffsll((long long)msk) - 1;
            vals[tt] = m;
            if (l == il) { cur = -DBL_MAX; sel = true; }
            if (l == tt)  myidxf = (float)il;
        }

        double ssum = 0.0;
#pragma unroll
        for (int tt = 0; tt < TOPK; ++tt) ssum += exp(vals[tt] - vals[0]);
        float p = sel ? (float)(exp(orig - vals[0]) / ssum) : 0.0f;

        outp[(size_t)row * E + l] = p;
        if (l < TOPK) outi[(size_t)row * TOPK + l] = myidxf;
    }
}

// ---------------------------------------------------------------------------
// Fallback (tiny ws): per-thread-row full fp64 from f32 W.  Correct, slow.
// ---------------------------------------------------------------------------
__global__ __launch_bounds__(64) void fallback_kernel(
    const float* __restrict__ x,
    const float* __restrict__ W,
    const float* __restrict__ b,
    float* __restrict__ outp,
    float* __restrict__ outi)
{
    const int row = blockIdx.x * 64 + threadIdx.x;
    double lg[64];
#pragma unroll
    for (int e = 0; e < 64; ++e) lg[e] = (double)b[e];
    const float* xr = x + (size_t)row * K;
    for (int k = 0; k < K; k += 4) {
        float4 xa = *reinterpret_cast<const float4*>(xr + k);
        double xd[4] = {(double)xa.x, (double)xa.y, (double)xa.z, (double)xa.w};
#pragma unroll
        for (int e = 0; e < 64; ++e) {
            const float* wp = W + (size_t)e * K + k;
            double a = lg[e];
#pragma unroll
            for (int j = 0; j < 4; ++j) a = fma(xd[j], (double)wp[j], a);
            lg[e] = a;
        }
    }
    unsigned long long selm = 0ull;
    double vals[TOPK]; int idx[TOPK];
#pragma unroll
    for (int i = 0; i < TOPK; ++i) {
        double m = -DBL_MAX; int mi = 0;
#pragma unroll
        for (int e = 0; e < 64; ++e) {
            bool gt = !((selm >> e) & 1ull) && (lg[e] > m);
            m = gt ? lg[e] : m; mi = gt ? e : mi;
        }
        vals[i] = m; idx[i] = mi; selm |= (1ull << mi);
    }
    double ssum = 0.0;
#pragma unroll
    for (int i = 0; i < TOPK; ++i) ssum += exp(vals[i] - vals[0]);
    double inv = 1.0 / ssum;
#pragma unroll
    for (int e = 0; e < 64; ++e)
        outp[(size_t)row * E + e] =
            ((selm >> e) & 1ull) ? (float)(exp(lg[e] - vals[0]) * inv) : 0.0f;
#pragma unroll
    for (int i = 0; i < TOPK; ++i)
        outi[(size_t)row * TOPK + i] = (float)idx[i];
}

// ---------------------------------------------------------------------------
extern "C" void kernel_launch(void* const* d_in, const int* in_sizes, int n_in,
                              void* d_out, int out_size, void* d_ws, size_t ws_size,
                              hipStream_t stream) {
    (void)in_sizes; (void)n_in; (void)out_size;
    const float* x = (const float*)d_in[0];
    const float* W = (const float*)d_in[1];
    const float* b = (const float*)d_in[2];

    float* outp = (float*)d_out;
    float* outi = outp + (size_t)M * E;

    const size_t wh_off   = 0;
    const size_t wl_off   = wh_off + sizeof(short) * (size_t)E * K;   // +512 KB
    const size_t cnt_off  = wl_off + sizeof(short) * (size_t)E * K;   // +512 KB
    const size_t list_off = cnt_off + 256;
    const size_t dsum_off = list_off + (size_t)M * sizeof(int);
    const size_t need     = dsum_off + (size_t)RCAP * FKS * E * sizeof(double);

    if (ws_size >= need) {
        short*  Whf  = (short*)((char*)d_ws + wh_off);
        short*  Wlf  = (short*)((char*)d_ws + wl_off);
        int*    cnt  = (int*)((char*)d_ws + cnt_off);
        int*    list = (int*)((char*)d_ws + list_off);
        double* dsum = (double*)((char*)d_ws + dsum_off);

        prep_kernel<<<(E * K) / 256, 256, 0, stream>>>(W, Whf, Wlf, cnt);
        gate_kernel<<<M / 16, 256, 0, stream>>>(x, Whf, Wlf, b, outp, outi, cnt, list);
        fix1_kernel<<<4096, 256, 0, stream>>>(x, W, dsum, cnt, list);
        fix2_kernel<<<1024, 64, 0, stream>>>(dsum, b, outp, outi, cnt, list);
    } else {
        fallback_kernel<<<M / 64, 64, 0, stream>>>(x, W, b, outp, outi);
    }
}

// Round 23
// 106.084 us; speedup vs baseline: 1.7660x; 1.7660x over previous
//
#include <hip/hip_runtime.h>
#include <cfloat>
#include <cmath>

#define M     16384
#define K     4096
#define E     64
#define TOPK  8
#define GAP_THRESH 1e-4f

#define RCAP  2048              // max rescued rows
#define FKS   8                 // rescue K-split

typedef __attribute__((ext_vector_type(8))) short bf16x8;
typedef __attribute__((ext_vector_type(4))) short s16x4;
typedef __attribute__((ext_vector_type(4))) float f32x4;

// ws layout: [Whf 512K][Wlf 512K][count 256B][list 64KB][dsum 8MB]

__device__ __forceinline__ short f2bf(float f) {           // RNE fp32->bf16
    unsigned u = __builtin_bit_cast(unsigned, f);
    u += 0x7FFFu + ((u >> 16) & 1u);
    return (short)(u >> 16);
}
__device__ __forceinline__ float bf2f(short h) {           // exact widen
    unsigned u = ((unsigned)(unsigned short)h) << 16;
    return __builtin_bit_cast(float, u);
}

// ---------------------------------------------------------------------------
// prep (r17-r22 byte-identical): Whf/Wlf in MFMA fragment order; zero count.
// ---------------------------------------------------------------------------
__global__ __launch_bounds__(256) void prep_kernel(const float* __restrict__ W,
                                                   short* __restrict__ Whf,
                                                   short* __restrict__ Wlf,
                                                   int* __restrict__ count) {
    int t = blockIdx.x * 256 + threadIdx.x;   // t = e*4096 + k
    float w = W[t];
    short h = f2bf(w);
    short lo = f2bf(w - bf2f(h));
    int e = t >> 12, k = t & 4095;
    int gc = k >> 5, kk = k & 31;
    size_t fidx = (((size_t)gc * 4 + (e >> 4)) * 64 + (kk >> 3) * 16 + (e & 15)) * 8
                  + (kk & 7);
    Whf[fidx] = h;
    Wlf[fidx] = lo;
    if (t == 0) *count = 0;
}

// ---------------------------------------------------------------------------
// MFMA gate, r23: cooperative bf16 LDS staging.
// r22 diagnosis: A-frag-pattern x loads touch ~64 cache lines/instr (4x the
// minimum) and all 4 waves duplicated the same loads AND f2bf conversions
// -> TA/L1-transaction-bound at ~0.8 TB/s.  Now per 128-k superchunk:
//  - flat fully-coalesced x loads (2 float4/thread, 16 lines/instr, 1 touch)
//  - ONE cooperative f32->bf16 hi/lo convert (cvt VALU / 4)
//  - swizzled LDS store (p = u ^ (r&7); uniform banks for b64 writes and
//    b128 A-frag reads), double-buffered, 2 barriers per superchunk.
// W: fragment-ordered 2-deep register pipeline (r12-proven).  Epilogue:
// fused ballot top-9 + flag (r21/r22-proven).  Grid M/16 = 1024.
// ---------------------------------------------------------------------------
__device__ __forceinline__ void mfma3(const bf16x8& ah, const bf16x8& al,
                                      const bf16x8& wh, const bf16x8& wl,
                                      f32x4& acc) {
    acc = __builtin_amdgcn_mfma_f32_16x16x32_bf16(ah, wh, acc, 0, 0, 0);
    acc = __builtin_amdgcn_mfma_f32_16x16x32_bf16(ah, wl, acc, 0, 0, 0);
    acc = __builtin_amdgcn_mfma_f32_16x16x32_bf16(al, wh, acc, 0, 0, 0);
}

__global__ __launch_bounds__(256) void gate_kernel(
    const float* __restrict__ x,
    const short* __restrict__ Whf,
    const short* __restrict__ Wlf,
    const float* __restrict__ b,
    float* __restrict__ outp,
    float* __restrict__ outi,
    int*   __restrict__ count,
    int*   __restrict__ list)
{
    __shared__ short lxh[2][16 * 128];   // 8 KB : bf16 hi, swizzled units
    __shared__ short lxl[2][16 * 128];   // 8 KB : bf16 lo
    __shared__ float llog[16 * E];       // 4 KB : logit tile

    const int t  = threadIdx.x;
    const int l  = t & 63;
    const int wv = t >> 6;               // 0..3 = expert group
    const int row0 = blockIdx.x * 16;

    // ---- x staging map: thread t loads/converts rows srA and srA+8 --------
    const int srA  = t >> 5;             // 0..7
    const int scol = t & 31;             // float4 column within 128-k slice
    const float* gxA = x + (size_t)(row0 + srA) * K + scol * 4;
    const float* gxB = x + (size_t)(row0 + 8 + srA) * K + scol * 4;
    // LDS b64 slot: unit u = scol>>1, half = scol&1, swizzle p = u^(r&7)
    const int pu   = (scol >> 1) ^ (srA & 7);          // (8+srA)&7 == srA&7
    const int offA = srA * 128 + pu * 8 + (scol & 1) * 4;
    const int offB = (8 + srA) * 128 + pu * 8 + (scol & 1) * 4;

#define CVTW(nb, v, off) do {                                          \
        s16x4 hh_, ll_;                                                \
        float vv_[4] = {(v).x, (v).y, (v).z, (v).w};                   \
        _Pragma("unroll")                                              \
        for (int j_ = 0; j_ < 4; ++j_) {                               \
            short h_ = f2bf(vv_[j_]);                                  \
            hh_[j_] = h_;                                              \
            ll_[j_] = f2bf(vv_[j_] - bf2f(h_));                        \
        }                                                              \
        *reinterpret_cast<s16x4*>(&lxh[nb][off]) = hh_;                \
        *reinterpret_cast<s16x4*>(&lxl[nb][off]) = ll_;                \
    } while (0)

    // ---- A-frag read offsets (swizzled): row r=l&15, unit u=q*4+(l>>4) ----
    int aoff[4];
#pragma unroll
    for (int q = 0; q < 4; ++q) {
        const int r = l & 15;
        const int u = q * 4 + (l >> 4);
        aoff[q] = r * 128 + (u ^ (r & 7)) * 8;
    }

    // ---- W fragment pointers (et = wv) ------------------------------------
    const short* ph = Whf + (size_t)wv * 512 + (size_t)l * 8;
    const short* pw = Wlf + (size_t)wv * 512 + (size_t)l * 8;

    f32x4 acc = {0, 0, 0, 0};

    // ---- prologue: stage superchunk 0 -------------------------------------
    {
        float4 a0 = *reinterpret_cast<const float4*>(gxA);
        float4 b0 = *reinterpret_cast<const float4*>(gxB);
        CVTW(0, a0, offA);
        CVTW(0, b0, offB);
    }
    __syncthreads();

    bf16x8 whA = *reinterpret_cast<const bf16x8*>(ph);       // chunk 0
    bf16x8 wlA = *reinterpret_cast<const bf16x8*>(pw);
    bf16x8 whB, wlB;

    for (int sc = 0; sc < 32; ++sc) {
        const int buf = sc & 1;
        float4 sA, sB;
        if (sc + 1 < 32) {               // issue next-SC stage loads early
            sA = *reinterpret_cast<const float4*>(gxA + (sc + 1) * 128);
            sB = *reinterpret_cast<const float4*>(gxB + (sc + 1) * 128);
        }

        const short* xh = lxh[buf];
        const short* xl = lxl[buf];
        const int c0 = sc * 4;

        // q0: compute chunk c0 (regs A), load c0+1 (regs B)
        whB = *reinterpret_cast<const bf16x8*>(ph + (size_t)(c0 + 1) * 2048);
        wlB = *reinterpret_cast<const bf16x8*>(pw + (size_t)(c0 + 1) * 2048);
        {
            bf16x8 ah = *reinterpret_cast<const bf16x8*>(&xh[aoff[0]]);
            bf16x8 al = *reinterpret_cast<const bf16x8*>(&xl[aoff[0]]);
            mfma3(ah, al, whA, wlA, acc);
        }
        // q1: compute c0+1 (B), load c0+2 (A)
        whA = *reinterpret_cast<const bf16x8*>(ph + (size_t)(c0 + 2) * 2048);
        wlA = *reinterpret_cast<const bf16x8*>(pw + (size_t)(c0 + 2) * 2048);
        {
            bf16x8 ah = *reinterpret_cast<const bf16x8*>(&xh[aoff[1]]);
            bf16x8 al = *reinterpret_cast<const bf16x8*>(&xl[aoff[1]]);
            mfma3(ah, al, whB, wlB, acc);
        }
        // q2: compute c0+2 (A), load c0+3 (B)
        whB = *reinterpret_cast<const bf16x8*>(ph + (size_t)(c0 + 3) * 2048);
        wlB = *reinterpret_cast<const bf16x8*>(pw + (size_t)(c0 + 3) * 2048);
        {
            bf16x8 ah = *reinterpret_cast<const bf16x8*>(&xh[aoff[2]]);
            bf16x8 al = *reinterpret_cast<const bf16x8*>(&xl[aoff[2]]);
            mfma3(ah, al, whA, wlA, acc);
        }
        // q3: compute c0+3 (B), load c0+4 (A, next SC's first chunk)
        if (c0 + 4 < 128) {
            whA = *reinterpret_cast<const bf16x8*>(ph + (size_t)(c0 + 4) * 2048);
            wlA = *reinterpret_cast<const bf16x8*>(pw + (size_t)(c0 + 4) * 2048);
        }
        {
            bf16x8 ah = *reinterpret_cast<const bf16x8*>(&xh[aoff[3]]);
            bf16x8 al = *reinterpret_cast<const bf16x8*>(&xl[aoff[3]]);
            mfma3(ah, al, whB, wlB, acc);
        }

        __syncthreads();                 // all waves done reading buf
        if (sc + 1 < 32) {
            CVTW(buf ^ 1, sA, offA);     // convert once, cooperatively
            CVTW(buf ^ 1, sB, offB);
        }
        __syncthreads();                 // next buffer visible
    }
#undef CVTW

    // ---- fused epilogue (r21/r22 verbatim) --------------------------------
    // D layout (verified r10-r22): row = (l>>4)*4 + r, col = wv*16 + (l&15)
#pragma unroll
    for (int r = 0; r < 4; ++r)
        llog[((l >> 4) * 4 + r) * E + wv * 16 + (l & 15)] = acc[r];
    __syncthreads();

    const float bv = b[l];
#pragma unroll 1
    for (int rr = 0; rr < 4; ++rr) {
        const int rloc = wv * 4 + rr;
        const int row  = row0 + rloc;
        const float orig = llog[rloc * E + l] + bv;

        float cur = orig;
        float vals[9];
        float myidxf = 0.0f;
        bool  sel = false;

#pragma unroll
        for (int i = 0; i < 9; ++i) {
            float m = cur;
#pragma unroll
            for (int off = 32; off > 0; off >>= 1)
                m = fmaxf(m, __shfl_xor(m, off, 64));
            unsigned long long msk = __ballot(cur == m);
            int il = __ffsll((long long)msk) - 1;
            vals[i] = m;
            if (l == il) { cur = -FLT_MAX; if (i < TOPK) sel = true; }
            if (i < TOPK && l == i) myidxf = (float)il;
        }

        float ssum = 0.0f;
#pragma unroll
        for (int i = 0; i < TOPK; ++i) ssum += expf(vals[i] - vals[0]);
        float p = sel ? (expf(orig - vals[0]) / ssum) : 0.0f;

        outp[(size_t)row * E + l] = p;
        if (l < TOPK) outi[(size_t)row * TOPK + l] = myidxf;

        float mingap = FLT_MAX;
#pragma unroll
        for (int i = 0; i < 8; ++i) mingap = fminf(mingap, vals[i] - vals[i + 1]);
        if (l == 0 && mingap < GAP_THRESH) {
            int pos = atomicAdd(count, 1);
            if (pos < M) list[pos] = row;
        }
    }
}

// ---------------------------------------------------------------------------
// fix1 (r20-r22 byte-identical): fp64 partial dots, K-split 8 across blocks.
// ---------------------------------------------------------------------------
__global__ __launch_bounds__(256) void fix1_kernel(
    const float* __restrict__ x,
    const float* __restrict__ W,
    double* __restrict__ dsum,          // [RCAP][FKS][E]
    const int* __restrict__ count,
    const int* __restrict__ list)
{
    __shared__ float xsl[512];
    const int t   = threadIdx.x;
    const int l   = t & 63;
    const int wv  = t >> 6;
    const int tot = min(*count, RCAP) * FKS;

    for (int p = blockIdx.x; p < tot; p += gridDim.x) {
        const int i   = p >> 3;
        const int ks  = p & 7;
        const int row = list[i];
        const int k0  = ks << 9;

        if (t < 128)
            reinterpret_cast<float4*>(xsl)[t] =
                reinterpret_cast<const float4*>(x + (size_t)row * K + k0)[t];
        __syncthreads();

        const float4* xs4 = reinterpret_cast<const float4*>(xsl);

#pragma unroll
        for (int g = 0; g < 2; ++g) {
            const int e0 = wv * 16 + g * 8;
            float4 w0[8], w1[8];
#pragma unroll
            for (int e8 = 0; e8 < 8; ++e8) {
                const float4* wp = reinterpret_cast<const float4*>(
                    W + (size_t)(e0 + e8) * K + k0);
                w0[e8] = wp[l];
                w1[e8] = wp[l + 64];
            }
            float4 xv0 = xs4[l];
            float4 xv1 = xs4[l + 64];

            double s[8];
#pragma unroll
            for (int e8 = 0; e8 < 8; ++e8) {
                double a = 0.0;
                a = fma((double)xv0.x, (double)w0[e8].x, a);
                a = fma((double)xv0.y, (double)w0[e8].y, a);
                a = fma((double)xv0.z, (double)w0[e8].z, a);
                a = fma((double)xv0.w, (double)w0[e8].w, a);
                a = fma((double)xv1.x, (double)w1[e8].x, a);
                a = fma((double)xv1.y, (double)w1[e8].y, a);
                a = fma((double)xv1.z, (double)w1[e8].z, a);
                a = fma((double)xv1.w, (double)w1[e8].w, a);
                s[e8] = a;
            }

#pragma unroll
            for (int e8 = 0; e8 < 8; ++e8) {
                double v = s[e8];
#pragma unroll
                for (int off = 32; off > 0; off >>= 1)
                    v += __shfl_xor(v, off, 64);
                if (l == 0)
                    dsum[((size_t)i * FKS + ks) * E + e0 + e8] = v;
            }
        }
        __syncthreads();
    }
}

// ---------------------------------------------------------------------------
// fix2 (r20-r22 byte-identical): combine partials + proven fp64 epilogue.
// ---------------------------------------------------------------------------
__global__ __launch_bounds__(64) void fix2_kernel(
    const double* __restrict__ dsum,
    const float*  __restrict__ b,
    float* __restrict__ outp,
    float* __restrict__ outi,
    const int* __restrict__ count,
    const int* __restrict__ list)
{
    const int l   = threadIdx.x;
    const int cnt = min(*count, RCAP);

    for (int i = blockIdx.x; i < cnt; i += gridDim.x) {
        const int row = list[i];

        double orig = (double)b[l];
#pragma unroll
        for (int ks = 0; ks < FKS; ++ks)
            orig += dsum[((size_t)i * FKS + ks) * E + l];

        double cur = orig;
        double vals[TOPK];
        float  myidxf = 0.0f;
        bool   sel = false;

#pragma unroll
        for (int tt = 0; tt < TOPK; ++tt) {
            double m = cur;
#pragma unroll
            for (int off = 32; off > 0; off >>= 1) {
                double o = __shfl_xor(m, off, 64);
                m = fmax(m, o);
            }
            unsigned long long msk = __ballot(cur == m);
            int il = __ffsll((long long)msk) - 1;
            vals[tt] = m;
            if (l == il) { cur = -DBL_MAX; sel = true; }
            if (l == tt)  myidxf = (float)il;
        }

        double ssum = 0.0;
#pragma unroll
        for (int tt = 0; tt < TOPK; ++tt) ssum += exp(vals[tt] - vals[0]);
        float p = sel ? (float)(exp(orig - vals[0]) / ssum) : 0.0f;

        outp[(size_t)row * E + l] = p;
        if (l < TOPK) outi[(size_t)row * TOPK + l] = myidxf;
    }
}

// ---------------------------------------------------------------------------
// Fallback (tiny ws): per-thread-row full fp64 from f32 W.  Correct, slow.
// ---------------------------------------------------------------------------
__global__ __launch_bounds__(64) void fallback_kernel(
    const float* __restrict__ x,
    const float* __restrict__ W,
    const float* __restrict__ b,
    float* __restrict__ outp,
    float* __restrict__ outi)
{
    const int row = blockIdx.x * 64 + threadIdx.x;
    double lg[64];
#pragma unroll
    for (int e = 0; e < 64; ++e) lg[e] = (double)b[e];
    const float* xr = x + (size_t)row * K;
    for (int k = 0; k < K; k += 4) {
        float4 xa = *reinterpret_cast<const float4*>(xr + k);
        double xd[4] = {(double)xa.x, (double)xa.y, (double)xa.z, (double)xa.w};
#pragma unroll
        for (int e = 0; e < 64; ++e) {
            const float* wp = W + (size_t)e * K + k;
            double a = lg[e];
#pragma unroll
            for (int j = 0; j < 4; ++j) a = fma(xd[j], (double)wp[j], a);
            lg[e] = a;
        }
    }
    unsigned long long selm = 0ull;
    double vals[TOPK]; int idx[TOPK];
#pragma unroll
    for (int i = 0; i < TOPK; ++i) {
        double m = -DBL_MAX; int mi = 0;
#pragma unroll
        for (int e = 0; e < 64; ++e) {
            bool gt = !((selm >> e) & 1ull) && (lg[e] > m);
            m = gt ? lg[e] : m; mi = gt ? e : mi;
        }
        vals[i] = m; idx[i] = mi; selm |= (1ull << mi);
    }
    double ssum = 0.0;
#pragma unroll
    for (int i = 0; i < TOPK; ++i) ssum += exp(vals[i] - vals[0]);
    double inv = 1.0 / ssum;
#pragma unroll
    for (int e = 0; e < 64; ++e)
        outp[(size_t)row * E + e] =
            ((selm >> e) & 1ull) ? (float)(exp(lg[e] - vals[0]) * inv) : 0.0f;
#pragma unroll
    for (int i = 0; i < TOPK; ++i)
        outi[(size_t)row * TOPK + i] = (float)idx[i];
}

// ---------------------------------------------------------------------------
extern "C" void kernel_launch(void* const* d_in, const int* in_sizes, int n_in,
                              void* d_out, int out_size, void* d_ws, size_t ws_size,
                              hipStream_t stream) {
    (void)in_sizes; (void)n_in; (void)out_size;
    const float* x = (const float*)d_in[0];
    const float* W = (const float*)d_in[1];
    const float* b = (const float*)d_in[2];

    float* outp = (float*)d_out;
    float* outi = outp + (size_t)M * E;

    const size_t wh_off   = 0;
    const size_t wl_off   = wh_off + sizeof(short) * (size_t)E * K;   // +512 KB
    const size_t cnt_off  = wl_off + sizeof(short) * (size_t)E * K;   // +512 KB
    const size_t list_off = cnt_off + 256;
    const size_t dsum_off = list_off + (size_t)M * sizeof(int);
    const size_t need     = dsum_off + (size_t)RCAP * FKS * E * sizeof(double);

    if (ws_size >= need) {
        short*  Whf  = (short*)((char*)d_ws + wh_off);
        short*  Wlf  = (short*)((char*)d_ws + wl_off);
        int*    cnt  = (int*)((char*)d_ws + cnt_off);
        int*    list = (int*)((char*)d_ws + list_off);
        double* dsum = (double*)((char*)d_ws + dsum_off);

        prep_kernel<<<(E * K) / 256, 256, 0, stream>>>(W, Whf, Wlf, cnt);
        gate_kernel<<<M / 16, 256, 0, stream>>>(x, Whf, Wlf, b, outp, outi, cnt, list);
        fix1_kernel<<<4096, 256, 0, stream>>>(x, W, dsum, cnt, list);
        fix2_kernel<<<1024, 64, 0, stream>>>(dsum, b, outp, outi, cnt, list);
    } else {
        fallback_kernel<<<M / 64, 64, 0, stream>>>(x, W, b, outp, outi);
    }
}